// Round 10
// baseline (70.527 us; speedup 1.0000x reference)
//
#include <hip/hip_runtime.h>
#include <math.h>

// CTransformer on MI355X, round 10: round-6 structure, but W operands are read
// DIRECTLY from L2 into registers (no LDS staging, no stage barriers) — W
// fragments have zero intra-block reuse, so staging bought only serialization.
//   k_prep     : Wqkv/Wout fp32->bf16 + pad_k/pad_v vectors (LN(0)=ln_b)
//   k_ln_qkv   : fused LayerNorm + QKV GEMM, 32-pix blocks, LDS = As+Ct (33 KB)
//   k_attn_proj: fused attention + out-proj, 32-pix blocks, LDS = Bt (17 KB)

#define NPIX 16384
#define HW   4096
#define CDIM 256

typedef short  bf16x8 __attribute__((ext_vector_type(8)));
typedef float  f32x4  __attribute__((ext_vector_type(4)));
typedef unsigned short u16x8 __attribute__((ext_vector_type(8)));

__device__ inline float bf2f(unsigned short u) {
    unsigned v = ((unsigned)u) << 16;
    return __builtin_bit_cast(float, v);
}
__device__ inline unsigned short f2bf(float f) {   // round-to-nearest-even
    unsigned u = __builtin_bit_cast(unsigned, f);
    u += 0x7FFFu + ((u >> 16) & 1u);
    return (unsigned short)(u >> 16);
}

// ---- prep: weight conversions + pad vectors --------------------------------
__global__ __launch_bounds__(256) void k_prep(const float* __restrict__ Wqkv,
                                              const float* __restrict__ Wout,
                                              const float* __restrict__ bqkv,
                                              const float* __restrict__ lnb,
                                              unsigned short* __restrict__ Wqkvbf,
                                              unsigned short* __restrict__ Woutbf,
                                              float* __restrict__ pads) {
    int bid = blockIdx.x, t = threadIdx.x;
    if (bid < 768) {
        int i = bid * 256 + t;
        Wqkvbf[i] = f2bf(Wqkv[i]);
    } else if (bid < 1024) {
        int i = (bid - 768) * 256 + t;
        Woutbf[i] = f2bf(Wout[i]);
    } else {
        int d = (bid - 1024) * 256 + t;    // 0..511; k rows 256..511, v rows 512..767
        int row = 256 + d;
        const float* wrow = Wqkv + (size_t)row * CDIM;
        float s = bqkv[row];
        for (int c = 0; c < CDIM; ++c) s += lnb[c] * wrow[c];
        pads[d] = s;
    }
}

// ---- FUSED LayerNorm + QKV GEMM --------------------------------------------
// Block: 32 pixels x 768 d, 256 threads (4 waves). Grid 512, XCD-swizzled.
// As[32][256] bf16 XOR-chunk swizzled; W read direct from L2 per fragment.
// Ct[32][264] for the transpose epilogue (LN scratch overlays it early).
__global__ __launch_bounds__(256, 3) void k_ln_qkv(const float* __restrict__ src,
                                                   const float* __restrict__ lnw,
                                                   const float* __restrict__ lnb,
                                                   const unsigned short* __restrict__ Wbf,
                                                   const float* __restrict__ bias,
                                                   unsigned short* __restrict__ qkvbf) {
    __shared__ unsigned short As[32 * 256];   // 16 KB
    __shared__ unsigned short Ct[32 * 264];   // 16.9 KB (also LN scratch early)

    int t = threadIdx.x;
    int bid = blockIdx.x;
    int sb = (bid & 7) * 64 + (bid >> 3);     // 512 = 8 XCDs x 64, bijective
    int n0 = sb * 32;
    int b = n0 >> 12, p0 = n0 & 4095;

    // ---- LN phase (scratch overlaid on Ct) ---------------------------------
    {
        float* red  = (float*)Ct;             // [8][33]
        float* red2 = red + 264;              // [8][33]
        float* muv  = red + 528;              // [32]
        float* rsv  = red + 560;              // [32]
        int pix = t & 31, q = t >> 5;
        const float* sp = src + ((size_t)b * CDIM) * HW + p0 + pix;
        float x[32];
        float sum = 0.f, sq = 0.f;
        #pragma unroll
        for (int i = 0; i < 32; ++i) {
            x[i] = sp[(size_t)(q * 32 + i) * HW];
            sum += x[i]; sq += x[i] * x[i];
        }
        red[q * 33 + pix] = sum; red2[q * 33 + pix] = sq;
        __syncthreads();
        if (t < 32) {
            float s = 0.f, s2 = 0.f;
            #pragma unroll
            for (int qq = 0; qq < 8; ++qq) { s += red[qq * 33 + t]; s2 += red2[qq * 33 + t]; }
            float mu = s * (1.f / 256.f);
            float var = fmaxf(s2 * (1.f / 256.f) - mu * mu, 0.f);
            muv[t] = mu; rsv[t] = rsqrtf(var + 1e-5f);
        }
        __syncthreads();
        float mu = muv[pix], rs = rsv[pix];
        #pragma unroll
        for (int c8 = 0; c8 < 4; ++c8) {
            u16x8 o8;
            #pragma unroll
            for (int j = 0; j < 8; ++j) {
                int c = q * 32 + c8 * 8 + j;
                float xn = (x[c8 * 8 + j] - mu) * rs * lnw[c] + lnb[c];
                o8[j] = f2bf(xn);
            }
            int chunk = q * 4 + c8;           // 0..31
            *(u16x8*)((char*)As + (pix * 512 + (((chunk & 7) ^ (pix & 7)) | (chunk & 24)) * 16)) = o8;
        }
    }
    __syncthreads();                          // As visible; LN scratch dead

    // ---- GEMM: 3 d-passes; W fragments loaded direct from L2 ---------------
    int lane = t & 63, wv = t >> 6;
    int lr = lane & 15, lg = lane >> 4;

    for (int pass = 0; pass < 3; ++pass) {
        int d0 = pass * 256;
        f32x4 acc[2][4] = {};
        for (int c = 0; c < 4; ++c) {
            #pragma unroll
            for (int kk = 0; kk < 2; ++kk) {
                int chA = c * 8 + kk * 4 + lg;      // 0..31 (global k chunk)
                bf16x8 a[2], bb[4];
                #pragma unroll
                for (int i = 0; i < 2; ++i) {
                    int r = i * 16 + lr;
                    int sl = ((chA & 7) ^ (r & 7)) | (chA & 24);
                    a[i] = *(bf16x8*)((char*)As + (r * 512 + sl * 16));
                }
                #pragma unroll
                for (int j = 0; j < 4; ++j)
                    bb[j] = *(const bf16x8*)(Wbf +
                        (size_t)(d0 + wv * 64 + j * 16 + lr) * 256 + c * 64 + kk * 32 + lg * 8);
                #pragma unroll
                for (int i = 0; i < 2; ++i)
                    #pragma unroll
                    for (int j = 0; j < 4; ++j)
                        acc[i][j] = __builtin_amdgcn_mfma_f32_16x16x32_bf16(
                            a[i], bb[j], acc[i][j], 0, 0, 0);
            }
        }
        // ---- epilogue: acc -> Ct[32][264] (+bias) -> coalesced stores ------
        __syncthreads();                      // prior Ct readers done
        #pragma unroll
        for (int j = 0; j < 4; ++j) {
            float bj = bias[d0 + wv * 64 + j * 16 + lr];
            #pragma unroll
            for (int i = 0; i < 2; ++i)
                #pragma unroll
                for (int r2 = 0; r2 < 4; ++r2)
                    Ct[(i * 16 + lg * 4 + r2) * 264 + wv * 64 + j * 16 + lr] =
                        f2bf(acc[i][j][r2] + bj);
        }
        __syncthreads();
        int row = t >> 3, cb = t & 7;         // 32 rows x 8 lanes
        #pragma unroll
        for (int s2 = 0; s2 < 4; ++s2) {
            int chunk = cb + 8 * s2;          // 0..31
            bf16x8 v = *(bf16x8*)(Ct + row * 264 + chunk * 8);
            *(bf16x8*)(qkvbf + (size_t)(n0 + row) * 768 + d0 + chunk * 8) = v;
        }
    }
}

// ---- FUSED attention + out-proj --------------------------------------------
// Block = 32 pixels x 256 out channels; 256 threads (4 waves). Grid 512,
// XCD-swizzled. Wout fragments read direct from L2; only Bt lives in LDS.
__global__ __launch_bounds__(256, 4) void k_attn_proj(const unsigned short* __restrict__ qkvbf,
                                                      const float* __restrict__ pads,
                                                      const unsigned short* __restrict__ Wbf,
                                                      const float* __restrict__ bias,
                                                      const float* __restrict__ src,
                                                      float* __restrict__ out) {
    __shared__ unsigned short Bt[32 * 264];   // attention out [pix][c] (16.9 KB)
    int t  = threadIdx.x;
    int bid = blockIdx.x;
    int sb  = (bid & 7) * 64 + (bid >> 3);    // 512 = 8 XCDs x 64, bijective
    int n0 = sb * 32;
    int b  = n0 >> 12;
    int p0 = n0 & 4095;

    // ---- phase 1: attention, thread = (pixel, head) ----
    {
        int pix = t >> 3, h = t & 7;
        int n = n0 + pix;
        int p = n & 4095, hh0 = p >> 6, ww0 = p & 63;
        const float scale = 0.1767766952966369f;  // 1/sqrt(32)

        float qv[32];
        const unsigned short* qp = qkvbf + (size_t)n * 768 + h * 32;
        #pragma unroll
        for (int c8 = 0; c8 < 4; ++c8) {
            bf16x8 v = *(const bf16x8*)(qp + c8 * 8);
            #pragma unroll
            for (int j = 0; j < 8; ++j) qv[c8 * 8 + j] = bf2f((unsigned short)v[j]) * scale;
        }
        float sc[9];
        #pragma unroll
        for (int t9 = 0; t9 < 9; ++t9) {
            int dy = t9 / 3 - 1, dx = t9 % 3 - 1;
            int hh = hh0 + dy, ww = ww0 + dx;
            bool ok = ((unsigned)hh < 64u) && ((unsigned)ww < 64u);
            float a = 0.f;
            if (ok) {
                const unsigned short* kp = qkvbf + (size_t)(n + dy * 64 + dx) * 768 + 256 + h * 32;
                #pragma unroll
                for (int c8 = 0; c8 < 4; ++c8) {
                    bf16x8 v = *(const bf16x8*)(kp + c8 * 8);
                    #pragma unroll
                    for (int j = 0; j < 8; ++j) a += qv[c8 * 8 + j] * bf2f((unsigned short)v[j]);
                }
            } else {
                const float* pk = pads + h * 32;
                #pragma unroll
                for (int j = 0; j < 32; ++j) a += qv[j] * pk[j];
            }
            sc[t9] = a;
        }
        float m = sc[0];
        #pragma unroll
        for (int t9 = 1; t9 < 9; ++t9) m = fmaxf(m, sc[t9]);
        float s = 0.f;
        #pragma unroll
        for (int t9 = 0; t9 < 9; ++t9) { sc[t9] = __expf(sc[t9] - m); s += sc[t9]; }
        float inv = 1.0f / s;

        float ov[32];
        #pragma unroll
        for (int j = 0; j < 32; ++j) ov[j] = 0.f;
        #pragma unroll
        for (int t9 = 0; t9 < 9; ++t9) {
            int dy = t9 / 3 - 1, dx = t9 % 3 - 1;
            int hh = hh0 + dy, ww = ww0 + dx;
            bool ok = ((unsigned)hh < 64u) && ((unsigned)ww < 64u);
            float w = sc[t9] * inv;
            if (ok) {
                const unsigned short* vp = qkvbf + (size_t)(n + dy * 64 + dx) * 768 + 512 + h * 32;
                #pragma unroll
                for (int c8 = 0; c8 < 4; ++c8) {
                    bf16x8 v = *(const bf16x8*)(vp + c8 * 8);
                    #pragma unroll
                    for (int j = 0; j < 8; ++j) ov[c8 * 8 + j] += w * bf2f((unsigned short)v[j]);
                }
            } else {
                const float* pv = pads + 256 + h * 32;
                #pragma unroll
                for (int j = 0; j < 32; ++j) ov[j] += w * pv[j];
            }
        }
        #pragma unroll
        for (int c8 = 0; c8 < 4; ++c8) {
            u16x8 o8;
            #pragma unroll
            for (int j = 0; j < 8; ++j) o8[j] = f2bf(ov[c8 * 8 + j]);
            *(u16x8*)(Bt + pix * 264 + h * 32 + c8 * 8) = o8;
        }
    }
    __syncthreads();   // Bt visible — the only barrier in this kernel

    // ---- phase 2: GEMM 256ch x 32pix x 256k; W direct from L2 ----
    int lane = t & 63, wv = t >> 6;
    int lr = lane & 15, lg = lane >> 4;
    f32x4 acc[4][2] = {};
    for (int kc = 0; kc < 8; ++kc) {
        bf16x8 a[4], bb[2];
        #pragma unroll
        for (int i = 0; i < 4; ++i)
            a[i] = *(const bf16x8*)(Wbf +
                (size_t)(wv * 64 + i * 16 + lr) * 256 + kc * 32 + lg * 8);
        #pragma unroll
        for (int j = 0; j < 2; ++j)
            bb[j] = *(bf16x8*)(Bt + (j * 16 + lr) * 264 + kc * 32 + lg * 8);
        #pragma unroll
        for (int i = 0; i < 4; ++i)
            #pragma unroll
            for (int j = 0; j < 2; ++j)
                acc[i][j] = __builtin_amdgcn_mfma_f32_16x16x32_bf16(
                    a[i], bb[j], acc[i][j], 0, 0, 0);
    }
    #pragma unroll
    for (int i = 0; i < 4; ++i) {
        #pragma unroll
        for (int r2 = 0; r2 < 4; ++r2) {
            int dg = wv * 64 + i * 16 + lg * 4 + r2;
            float bd = bias[dg];
            #pragma unroll
            for (int j = 0; j < 2; ++j) {
                int ng = p0 + j * 16 + lr;
                size_t idx = ((size_t)(b * CDIM + dg)) * HW + ng;
                out[idx] = acc[i][j][r2] + bd + src[idx];
            }
        }
    }
}

extern "C" void kernel_launch(void* const* d_in, const int* in_sizes, int n_in,
                              void* d_out, int out_size, void* d_ws, size_t ws_size,
                              hipStream_t stream) {
    const float* src  = (const float*)d_in[0];
    const float* lnw  = (const float*)d_in[1];
    const float* lnb  = (const float*)d_in[2];
    const float* Wqkv = (const float*)d_in[3];
    const float* bqkv = (const float*)d_in[4];
    const float* Wout = (const float*)d_in[5];
    const float* bout = (const float*)d_in[6];
    float* out = (float*)d_out;

    unsigned short* qkvbf  = (unsigned short*)d_ws;               // 16384*768
    unsigned short* Wqkvbf = qkvbf + (size_t)NPIX * 768;          // 768*256
    unsigned short* Woutbf = Wqkvbf + 768 * 256;                  // 256*256
    float* pads = (float*)(Woutbf + 256 * 256);                   // 512 floats

    k_prep<<<1026, 256, 0, stream>>>(Wqkv, Wout, bqkv, lnb, Wqkvbf, Woutbf, pads);
    k_ln_qkv<<<512, 256, 0, stream>>>(src, lnw, lnb, Wqkvbf, bqkv, qkvbf);
    k_attn_proj<<<512, 256, 0, stream>>>(qkvbf, pads, Woutbf, bout, src, out);
}

// Round 12
// 50.924 us; speedup vs baseline: 1.3850x; 1.3850x over previous
//
#include <hip/hip_runtime.h>
#include <math.h>

// CTransformer on MI355X, round 12: per-wave W staging (round-11 design) with
// the LN-scratch/prefetch overlay race FIXED (dedicated scratch) and explicit
// per-wave vmcnt(0)+sched_barrier fences before reading staged buffers.
//   k_prep     : Wqkv/Wout fp32->bf16 + pad vectors (parallel shuffle dots)
//   k_ln_qkv   : fused LN + QKV GEMM; 2 block barriers total
//   k_attn_proj: fused attention + out-proj; 1 block barrier total

#define NPIX 16384
#define HW   4096
#define CDIM 256

typedef short  bf16x8 __attribute__((ext_vector_type(8)));
typedef float  f32x4  __attribute__((ext_vector_type(4)));
typedef unsigned short u16x8 __attribute__((ext_vector_type(8)));

__device__ inline float bf2f(unsigned short u) {
    unsigned v = ((unsigned)u) << 16;
    return __builtin_bit_cast(float, v);
}
__device__ inline unsigned short f2bf(float f) {   // round-to-nearest-even
    unsigned u = __builtin_bit_cast(unsigned, f);
    u += 0x7FFFu + ((u >> 16) & 1u);
    return (unsigned short)(u >> 16);
}

__device__ inline void wave_fence_vm0() {
    asm volatile("s_waitcnt vmcnt(0)" ::: "memory");
    __builtin_amdgcn_sched_barrier(0);
}

// ---- prep: weight conversions + pad vectors --------------------------------
__global__ __launch_bounds__(256) void k_prep(const float* __restrict__ Wqkv,
                                              const float* __restrict__ Wout,
                                              const float* __restrict__ bqkv,
                                              const float* __restrict__ lnb,
                                              unsigned short* __restrict__ Wqkvbf,
                                              unsigned short* __restrict__ Woutbf,
                                              float* __restrict__ pads) {
    int bid = blockIdx.x, t = threadIdx.x;
    if (bid < 768) {
        int i = bid * 256 + t;
        Wqkvbf[i] = f2bf(Wqkv[i]);
    } else if (bid < 1024) {
        int i = (bid - 768) * 256 + t;
        Woutbf[i] = f2bf(Wout[i]);
    } else {
        int tg = (bid - 1024) * 256 + t;   // 8192 threads; 16 lanes per output
        int d = tg >> 4, part = tg & 15;
        int row = 256 + d;                 // k rows 256..511, v rows 512..767
        const float* wr = Wqkv + (size_t)row * CDIM + part * 16;
        float s = 0.f;
        #pragma unroll
        for (int c = 0; c < 16; ++c) s += lnb[part * 16 + c] * wr[c];
        s += __shfl_xor(s, 1);
        s += __shfl_xor(s, 2);
        s += __shfl_xor(s, 4);
        s += __shfl_xor(s, 8);
        if (part == 0) pads[d] = s + bqkv[row];
    }
}

// ---- per-wave stage: 64 rows x 32 k bf16 (4 KB) into wave-private LDS ------
// Linear dest [64][32] u16; source-side swizzle: slot s of row r holds source
// chunk s ^ ((r>>1)&3).
__device__ inline void stage32(const unsigned short* __restrict__ g, int grow0,
                               int koff, unsigned short* dst, int lane) {
    int r16  = lane >> 2;
    int slot = lane & 3;
    #pragma unroll
    for (int it = 0; it < 4; ++it) {
        int row = it * 16 + r16;           // wave-local 0..63
        const unsigned short* src = g + (size_t)(grow0 + row) * 256 + koff
                                      + ((slot ^ ((row >> 1) & 3)) * 8);
        __builtin_amdgcn_global_load_lds(
            (const __attribute__((address_space(1))) void*)src,
            (__attribute__((address_space(3))) void*)(dst + it * 16 * 32),
            16, 0, 0);
    }
}

// ---- FUSED LayerNorm + QKV GEMM --------------------------------------------
// Block: 32 pixels x 768 d, 256 threads (4 waves). Grid 512, XCD-swizzled.
// As[32][256] XOR-chunk swizzled (block-shared). W: per-wave [2][64][32] dbuf.
// LN scratch is DEDICATED (not overlaid on staging destinations).
__global__ __launch_bounds__(256, 3) void k_ln_qkv(const float* __restrict__ src,
                                                   const float* __restrict__ lnw,
                                                   const float* __restrict__ lnb,
                                                   const unsigned short* __restrict__ Wbf,
                                                   const float* __restrict__ bias,
                                                   unsigned short* __restrict__ qkvbf) {
    __shared__ unsigned short As[32 * 256];    // 16 KB
    __shared__ unsigned short Bs[4 * 4096];    // 32 KB: per-wave [2][64][32] dbuf
    __shared__ float redS[8 * 33 * 2 + 64];    // 2.4 KB dedicated LN scratch

    int t = threadIdx.x;
    int bid = blockIdx.x;
    int sb = (bid & 7) * 64 + (bid >> 3);      // 512 = 8 XCDs x 64, bijective
    int n0 = sb * 32;
    int b = n0 >> 12, p0 = n0 & 4095;
    int lane = t & 63, wv = t >> 6;
    int lr = lane & 15, lg = lane >> 4;
    unsigned short* BsW = Bs + wv * 4096;      // wave-private 8 KB

    // prologue prefetch (safe: LN scratch is separate memory)
    stage32(Wbf, wv * 64, 0, BsW, lane);       // g=0 -> buf0

    // ---- LN phase ----------------------------------------------------------
    {
        float* red  = redS;                    // [8][33]
        float* red2 = redS + 264;              // [8][33]
        float* muv  = redS + 528;              // [32]
        float* rsv  = redS + 560;              // [32]
        int pix = t & 31, q = t >> 5;
        const float* sp = src + ((size_t)b * CDIM) * HW + p0 + pix;
        float x[32];
        float sum = 0.f, sq = 0.f;
        #pragma unroll
        for (int i = 0; i < 32; ++i) {
            x[i] = sp[(size_t)(q * 32 + i) * HW];
            sum += x[i]; sq += x[i] * x[i];
        }
        red[q * 33 + pix] = sum; red2[q * 33 + pix] = sq;
        __syncthreads();
        if (t < 32) {
            float s = 0.f, s2 = 0.f;
            #pragma unroll
            for (int qq = 0; qq < 8; ++qq) { s += red[qq * 33 + t]; s2 += red2[qq * 33 + t]; }
            float mu = s * (1.f / 256.f);
            float var = fmaxf(s2 * (1.f / 256.f) - mu * mu, 0.f);
            muv[t] = mu; rsv[t] = rsqrtf(var + 1e-5f);
        }
        __syncthreads();
        float mu = muv[pix], rs = rsv[pix];
        #pragma unroll
        for (int c8 = 0; c8 < 4; ++c8) {
            u16x8 o8;
            #pragma unroll
            for (int j = 0; j < 8; ++j) {
                int c = q * 32 + c8 * 8 + j;
                float xn = (x[c8 * 8 + j] - mu) * rs * lnw[c] + lnb[c];
                o8[j] = f2bf(xn);
            }
            int chunk = q * 4 + c8;            // 0..31
            *(u16x8*)((char*)As + (pix * 512 + (((chunk & 7) ^ (pix & 7)) | (chunk & 24)) * 16)) = o8;
        }
    }
    __syncthreads();   // As visible to all waves. LAST block barrier.

    // ---- K-loop: 3 passes x 8 chunks; per-wave dbuf, per-wave fences -------
    for (int pass = 0; pass < 3; ++pass) {
        int d0 = pass * 256;
        f32x4 acc[2][4] = {};
        #pragma unroll
        for (int kc = 0; kc < 8; ++kc) {
            int g = pass * 8 + kc;
            wave_fence_vm0();                  // buf[g&1] staged & landed
            const unsigned short* B = BsW + (g & 1) * 2048;
            int chA = kc * 4 + lg;             // As k-chunk 0..31
            bf16x8 a[2], bb[4];
            #pragma unroll
            for (int i = 0; i < 2; ++i) {
                int r = i * 16 + lr;
                int sl = ((chA & 7) ^ (r & 7)) | (chA & 24);
                a[i] = *(bf16x8*)((char*)As + (r * 512 + sl * 16));
            }
            #pragma unroll
            for (int j = 0; j < 4; ++j) {
                int rb = j * 16 + lr;          // wave-local W row 0..63
                int sl = lg ^ ((rb >> 1) & 3);
                bb[j] = *(bf16x8*)(B + rb * 32 + sl * 8);
            }
            if (kc < 7)                        // prefetch next chunk, other half
                stage32(Wbf, d0 + wv * 64, (kc + 1) * 32,
                        BsW + ((g + 1) & 1) * 2048, lane);
            #pragma unroll
            for (int i = 0; i < 2; ++i)
                #pragma unroll
                for (int j = 0; j < 4; ++j)
                    acc[i][j] = __builtin_amdgcn_mfma_f32_16x16x32_bf16(
                        a[i], bb[j], acc[i][j], 0, 0, 0);
        }
        // ---- per-wave epilogue: Ct[32][72] in wave's own 8 KB --------------
        // (DS ops are in-order per wave: writes ordered after the kc=7 reads;
        //  no stage is in flight here — last prefetch was kc==6 -> consumed.)
        unsigned short* Ct = BsW;
        #pragma unroll
        for (int j = 0; j < 4; ++j) {
            float bj = bias[d0 + wv * 64 + j * 16 + lr];
            #pragma unroll
            for (int i = 0; i < 2; ++i)
                #pragma unroll
                for (int r2 = 0; r2 < 4; ++r2)
                    Ct[(i * 16 + lg * 4 + r2) * 72 + j * 16 + lr] =
                        f2bf(acc[i][j][r2] + bj);
        }
        #pragma unroll
        for (int it2 = 0; it2 < 4; ++it2) {
            int row = 8 * it2 + (lane >> 3);   // 0..31
            int chunk = lane & 7;              // wave's 64 cols = 8 chunks
            bf16x8 v = *(bf16x8*)(Ct + row * 72 + chunk * 8);
            *(bf16x8*)(qkvbf + (size_t)(n0 + row) * 768 + d0 + wv * 64 + chunk * 8) = v;
        }
        if (pass < 2)                          // next pass chunk0 -> buf0
            stage32(Wbf, (pass + 1) * 256 + wv * 64, 0, BsW, lane);
    }
}

// ---- FUSED attention + out-proj --------------------------------------------
// Block = 32 pixels x 256 out channels; 256 threads (4 waves). Grid 512,
// XCD-swizzled. Wout: per-wave dbuf staging; ONE block barrier (Bt).
__global__ __launch_bounds__(256, 3) void k_attn_proj(const unsigned short* __restrict__ qkvbf,
                                                      const float* __restrict__ pads,
                                                      const unsigned short* __restrict__ Wbf,
                                                      const float* __restrict__ bias,
                                                      const float* __restrict__ src,
                                                      float* __restrict__ out) {
    __shared__ unsigned short Bt[32 * 264];    // attention out [pix][c] (16.9 KB)
    __shared__ unsigned short Ws[4 * 4096];    // 32 KB: per-wave [2][64][32] dbuf
    int t  = threadIdx.x;
    int bid = blockIdx.x;
    int sb  = (bid & 7) * 64 + (bid >> 3);     // 512 = 8 XCDs x 64, bijective
    int n0 = sb * 32;
    int b  = n0 >> 12;
    int p0 = n0 & 4095;
    int lane = t & 63, wv = t >> 6;
    int lr = lane & 15, lg = lane >> 4;
    unsigned short* WsW = Ws + wv * 4096;      // wave-private 8 KB

    stage32(Wbf, wv * 64, 0, WsW, lane);       // buf0; hides under attention

    // ---- phase 1: attention, thread = (pixel, head) ----
    {
        int pix = t >> 3, h = t & 7;
        int n = n0 + pix;
        int p = n & 4095, hh0 = p >> 6, ww0 = p & 63;
        const float scale = 0.1767766952966369f;  // 1/sqrt(32)

        float qv[32];
        const unsigned short* qp = qkvbf + (size_t)n * 768 + h * 32;
        #pragma unroll
        for (int c8 = 0; c8 < 4; ++c8) {
            bf16x8 v = *(const bf16x8*)(qp + c8 * 8);
            #pragma unroll
            for (int j = 0; j < 8; ++j) qv[c8 * 8 + j] = bf2f((unsigned short)v[j]) * scale;
        }
        float sc[9];
        #pragma unroll
        for (int t9 = 0; t9 < 9; ++t9) {
            int dy = t9 / 3 - 1, dx = t9 % 3 - 1;
            int hh = hh0 + dy, ww = ww0 + dx;
            bool ok = ((unsigned)hh < 64u) && ((unsigned)ww < 64u);
            float a = 0.f;
            if (ok) {
                const unsigned short* kp = qkvbf + (size_t)(n + dy * 64 + dx) * 768 + 256 + h * 32;
                #pragma unroll
                for (int c8 = 0; c8 < 4; ++c8) {
                    bf16x8 v = *(const bf16x8*)(kp + c8 * 8);
                    #pragma unroll
                    for (int j = 0; j < 8; ++j) a += qv[c8 * 8 + j] * bf2f((unsigned short)v[j]);
                }
            } else {
                const float* pk = pads + h * 32;
                #pragma unroll
                for (int j = 0; j < 32; ++j) a += qv[j] * pk[j];
            }
            sc[t9] = a;
        }
        float m = sc[0];
        #pragma unroll
        for (int t9 = 1; t9 < 9; ++t9) m = fmaxf(m, sc[t9]);
        float s = 0.f;
        #pragma unroll
        for (int t9 = 0; t9 < 9; ++t9) { sc[t9] = __expf(sc[t9] - m); s += sc[t9]; }
        float inv = 1.0f / s;

        float ov[32];
        #pragma unroll
        for (int j = 0; j < 32; ++j) ov[j] = 0.f;
        #pragma unroll
        for (int t9 = 0; t9 < 9; ++t9) {
            int dy = t9 / 3 - 1, dx = t9 % 3 - 1;
            int hh = hh0 + dy, ww = ww0 + dx;
            bool ok = ((unsigned)hh < 64u) && ((unsigned)ww < 64u);
            float w = sc[t9] * inv;
            if (ok) {
                const unsigned short* vp = qkvbf + (size_t)(n + dy * 64 + dx) * 768 + 512 + h * 32;
                #pragma unroll
                for (int c8 = 0; c8 < 4; ++c8) {
                    bf16x8 v = *(const bf16x8*)(vp + c8 * 8);
                    #pragma unroll
                    for (int j = 0; j < 8; ++j) ov[c8 * 8 + j] += w * bf2f((unsigned short)v[j]);
                }
            } else {
                const float* pv = pads + 256 + h * 32;
                #pragma unroll
                for (int j = 0; j < 32; ++j) ov[j] += w * pv[j];
            }
        }
        #pragma unroll
        for (int c8 = 0; c8 < 4; ++c8) {
            u16x8 o8;
            #pragma unroll
            for (int j = 0; j < 8; ++j) o8[j] = f2bf(ov[c8 * 8 + j]);
            *(u16x8*)(Bt + pix * 264 + h * 32 + c8 * 8) = o8;
        }
    }
    __syncthreads();   // Bt visible — the only block barrier

    // ---- phase 2: GEMM 256ch x 32pix x 256k; per-wave dbuf + fences ----
    f32x4 acc[4][2] = {};
    #pragma unroll
    for (int kc = 0; kc < 8; ++kc) {
        wave_fence_vm0();                      // buf[kc&1] landed
        const unsigned short* A = WsW + (kc & 1) * 2048;
        bf16x8 a[4], bb[2];
        #pragma unroll
        for (int i = 0; i < 4; ++i) {
            int ri = i * 16 + lr;              // wave-local W row 0..63
            int sl = lg ^ ((ri >> 1) & 3);
            a[i] = *(bf16x8*)(A + ri * 32 + sl * 8);
        }
        #pragma unroll
        for (int j = 0; j < 2; ++j)
            bb[j] = *(bf16x8*)(Bt + (j * 16 + lr) * 264 + kc * 32 + lg * 8);
        if (kc < 7)
            stage32(Wbf, wv * 64, (kc + 1) * 32, WsW + ((kc + 1) & 1) * 2048, lane);
        #pragma unroll
        for (int i = 0; i < 4; ++i)
            #pragma unroll
            for (int j = 0; j < 2; ++j)
                acc[i][j] = __builtin_amdgcn_mfma_f32_16x16x32_bf16(
                    a[i], bb[j], acc[i][j], 0, 0, 0);
    }
    #pragma unroll
    for (int i = 0; i < 4; ++i) {
        #pragma unroll
        for (int r2 = 0; r2 < 4; ++r2) {
            int dg = wv * 64 + i * 16 + lg * 4 + r2;
            float bd = bias[dg];
            #pragma unroll
            for (int j = 0; j < 2; ++j) {
                int ng = p0 + j * 16 + lr;
                size_t idx = ((size_t)(b * CDIM + dg)) * HW + ng;
                out[idx] = acc[i][j][r2] + bd + src[idx];
            }
        }
    }
}

extern "C" void kernel_launch(void* const* d_in, const int* in_sizes, int n_in,
                              void* d_out, int out_size, void* d_ws, size_t ws_size,
                              hipStream_t stream) {
    const float* src  = (const float*)d_in[0];
    const float* lnw  = (const float*)d_in[1];
    const float* lnb  = (const float*)d_in[2];
    const float* Wqkv = (const float*)d_in[3];
    const float* bqkv = (const float*)d_in[4];
    const float* Wout = (const float*)d_in[5];
    const float* bout = (const float*)d_in[6];
    float* out = (float*)d_out;

    unsigned short* qkvbf  = (unsigned short*)d_ws;               // 16384*768
    unsigned short* Wqkvbf = qkvbf + (size_t)NPIX * 768;          // 768*256
    unsigned short* Woutbf = Wqkvbf + 768 * 256;                  // 256*256
    float* pads = (float*)(Woutbf + 256 * 256);                   // 512 floats

    k_prep<<<1056, 256, 0, stream>>>(Wqkv, Wout, bqkv, lnb, Wqkvbf, Woutbf, pads);
    k_ln_qkv<<<512, 256, 0, stream>>>(src, lnw, lnb, Wqkvbf, bqkv, qkvbf);
    k_attn_proj<<<512, 256, 0, stream>>>(qkvbf, pads, Woutbf, bout, src, out);
}